// Round 7
// baseline (90.595 us; speedup 1.0000x reference)
//
#include <hip/hip_runtime.h>

// NEUROPULS unitary mesh, N=256 — R10: row-split across 4 waves per column.
// R9 post-mortem: per-stage cost ~750 cy is invariant to instruction count
// (55..130 VALU), memory source (global/LDS/none), and VGPR budget — the
// binding constraint is ONE wave per CU running a serial chain: 3 of 4
// SIMDs idle, and a lone wave can't hide its own issue+latency bubbles.
// Fix: 256-thread blocks; lane owns ONE row (tid), 4 waves share the
// stage chain. mstep partner = lane^1 (quad_perm DPP); crossing partner =
// lane+-1 (wave_shr/shl DPP, HW-verified in passing R6/R9); the two wave-
// boundary lanes exchange via a 128 B double-buffered LDS slot with one
// barrier per stage (4 waves on 4 SIMDs of one CU -> cheap).
// Per-lane collapsed operator (same verified algebra as R6/R8/R9):
//   out = K*own + G*partner,  K = U*p_own - W*p_partner (covers both E,F),
//   G = i*g*(p_own+p_partner);  U=AT^2, W=AR^2, g=AT*AR.
// Crossing: out = BT*own + i*BR*partner; rows 0,255 thru = BR*own.

__device__ __forceinline__ float dpp_xor1(float x) {  // quad_perm [1,0,3,2]
    return __int_as_float(__builtin_amdgcn_update_dpp(
        __float_as_int(x), __float_as_int(x), 0xB1, 0xf, 0xf, false));
}
__device__ __forceinline__ float dpp_up1(float x) {   // wave_shr:1, n <- n-1
    return __int_as_float(__builtin_amdgcn_update_dpp(
        __float_as_int(x), __float_as_int(x), 0x138, 0xf, 0xf, false));
}
__device__ __forceinline__ float dpp_dn1(float x) {   // wave_shl:1, n <- n+1
    return __int_as_float(__builtin_amdgcn_update_dpp(
        __float_as_int(x), __float_as_int(x), 0x130, 0xf, 0xf, false));
}

__global__ __launch_bounds__(256, 1)
void neuropuls_mesh_kernel(const float* __restrict__ thetas,  // [130,256] fp32
                           float* __restrict__ out)           // re[65536] || im[65536]
{
    constexpr int N = 256;
    __shared__ float thlds[128 * N];   // 128 KiB: theta rows 1..128
    __shared__ float bnd[2][4][4];     // [stage parity][wave][vr0,vi0,vr63,vi63]

    const int tid  = threadIdx.x;      // 0..255 == row index
    const int lane = tid & 63;
    const int w    = tid >> 6;         // wave 0..3
    const int col  = blockIdx.x;       // 0..255

    const float U  = 0.98f * 0.505f;                  // AT^2
    const float W  = 0.98f * 0.495f;                  // AR^2
    const float Gg = 0.98f * sqrtf(0.505f * 0.495f);  // AT*AR
    const float BT = sqrtf(0.98f * 0.01f);            // CR a*sqrt(CT)
    const float BR = sqrtf(0.98f * 0.99f);            // CR thru amplitude

    // ---- prologue: stage theta rows 1..128 -> LDS (coalesced float4) ----
    {
        const float4* s4 = (const float4*)(thetas + N);
        float4*       d4 = (float4*)thlds;
        #pragma unroll
        for (int k = 0; k < 32; ++k)
            d4[tid + k * 256] = s4[tid + k * 256];
    }

    // init: column `col` of diag(exp(i*theta[0]))
    float vr = 0.f, vi = 0.f;
    {
        float s0, c0;
        __sincosf(thetas[col], &s0, &c0);
        if (tid == col) { vr = c0; vi = s0; }
    }
    __syncthreads();   // theta staged; all waves may read

    const bool odd  = (tid & 1) != 0;
    const bool thru = (tid == 0) || (tid == N - 1);
    const float* tl = thlds + tid;

    // per-lane coefficients for one stage (off the serial chain)
    auto prep = [&](float th, float& Kr, float& Ki, float& Gr, float& Gi) {
        float s, c;
        __sincosf(th, &s, &c);
        const float cp = dpp_xor1(c);   // partner's cos
        const float sp = dpp_xor1(s);   // partner's sin
        Kr = U * c - W * cp;
        Ki = U * s - W * sp;
        Gr = -Gg * (s + sp);
        Gi =  Gg * (c + cp);
    };

    float Kr, Ki, Gr, Gi;
    prep(tl[0], Kr, Ki, Gr, Gi);       // coefs for stage 1 (theta[1])
    float thA = tl[256];               // theta[2]

    // crossing stages s = 1..127
    for (int s = 1; s <= 127; ++s) {
        // theta[s+2] (clamped at 128; post-loop thA is unused)
        const float thB = tl[(s < 127 ? s + 1 : 127) * 256];
        float Kr2, Ki2, Gr2, Gi2;
        prep(thA, Kr2, Ki2, Gr2, Gi2); // coefs for stage s+1, off-chain

        // ---- mstep: out = K*own + G*partner(lane^1) ----
        {
            const float pr = dpp_xor1(vr), pi = dpp_xor1(vi);
            const float nr = Kr * vr - Ki * vi + Gr * pr - Gi * pi;
            const float ni = Kr * vi + Ki * vr + Gr * pi + Gi * pr;
            vr = nr; vi = ni;
        }

        // ---- crossing: partner = lane+-1; boundary via LDS ----
        const int p = s & 1;
        if (lane == 0)  { bnd[p][w][0] = vr; bnd[p][w][1] = vi; }
        if (lane == 63) { bnd[p][w][2] = vr; bnd[p][w][3] = vi; }
        __syncthreads();
        {
            const float ur = dpp_up1(vr), ui = dpp_up1(vi);  // from lane-1
            const float dr = dpp_dn1(vr), di = dpp_dn1(vi);  // from lane+1
            float pr = odd ? dr : ur;   // odd row pairs with row+1, even with row-1
            float pi = odd ? di : ui;
            if (lane == 0) {            // row 64w (even): needs prev wave lane 63
                const int pw = (w > 0) ? w - 1 : 0;   // w==0 masked by thru
                pr = bnd[p][pw][2]; pi = bnd[p][pw][3];
            }
            if (lane == 63) {           // row 64w+63 (odd): needs next wave lane 0
                const int nw = (w < 3) ? w + 1 : 3;   // w==3 masked by thru
                pr = bnd[p][nw][0]; pi = bnd[p][nw][1];
            }
            const float nr = BT * vr - BR * pi;
            const float ni = BT * vi + BR * pr;
            vr = thru ? BR * vr : nr;
            vi = thru ? BR * vi : ni;
        }

        Kr = Kr2; Ki = Ki2; Gr = Gr2; Gi = Gi2;
        thA = thB;
    }

    // stage 128: mstep only (K = coefs(theta[128]))
    {
        const float pr = dpp_xor1(vr), pi = dpp_xor1(vi);
        const float nr = Kr * vr - Ki * vi + Gr * pr - Gi * pi;
        const float ni = Kr * vi + Ki * vr + Gr * pi + Gi * pr;
        vr = nr; vi = ni;
    }

    // final phase layer theta[129] (global, one-time)
    {
        float s9, c9;
        __sincosf(thetas[129 * N + tid], &s9, &c9);
        const float nr = c9 * vr - s9 * vi;
        const float ni = c9 * vi + s9 * vr;
        vr = nr; vi = ni;
    }

    // store PLANAR: real block then imag block, row-major [row][col]
    out[tid * N + col]         = vr;
    out[N * N + tid * N + col] = vi;
}

extern "C" void kernel_launch(void* const* d_in, const int* in_sizes, int n_in,
                              void* d_out, int out_size, void* d_ws, size_t ws_size,
                              hipStream_t stream)
{
    const float* thetas = (const float*)d_in[0];   // [130,256] fp32
    float* out = (float*)d_out;                    // planar: re[65536] || im[65536]
    (void)in_sizes; (void)n_in; (void)out_size; (void)d_ws; (void)ws_size;
    neuropuls_mesh_kernel<<<dim3(256), dim3(256), 0, stream>>>(thetas, out);
}

// Round 8
// 77.669 us; speedup vs baseline: 1.1664x; 1.1664x over previous
//
#include <hip/hip_runtime.h>

// NEUROPULS unitary mesh, N=256 — R11: precomputed coefs + chunked
// global_load_lds double-buffer with counted vmcnt (T3/T4 pattern).
// R10 post-mortem: wall ~40-44 us invariant across instr count (60..180),
// memory source, VGPR budget, and 1-vs-4-wave parallelism. Back-computed
// issue duty from VALUBusy says the wall = issue + one exposed memory
// latency per stage (at the real, likely-downclocked rate). So cut BOTH:
//  - R8's coef kernel removes sincos/prep from the loop (~58 instr/stage);
//  - coefs live in LDS via 8-stage 24KB chunks, double-buffered with
//    __builtin_amdgcn_global_load_lds(16B) + s_waitcnt vmcnt(24) (never 0
//    in-loop), sched_barrier(0) after waits. No barrier (1 wave/block).
// DMA dest = uniform base + lane*16, linear; source per-lane contiguous.
// Coef layout (float4): [(stage*3 + g)*64 + lane], g in {A,B,C}:
//   A=(Er0,Ei0,Fr0,Fi0)  B=(Gr0,Gi0,Gr1,Gi1)  C=(Er1,Ei1,Fr1,Fi1)
//   E=U*p0-W*p1, F=U*p1-W*p0, G=i*g*(p0+p1); U=AT^2, W=AR^2, g=AT*AR
// (same verified algebra/values as passing R8/R9/R10).

__device__ __forceinline__ float dpp_up1(float x) {   // wave_shr:1, n <- n-1
    return __int_as_float(__builtin_amdgcn_update_dpp(
        __float_as_int(x), __float_as_int(x), 0x138, 0xf, 0xf, false));
}
__device__ __forceinline__ float dpp_dn1(float x) {   // wave_shl:1, n <- n+1
    return __int_as_float(__builtin_amdgcn_update_dpp(
        __float_as_int(x), __float_as_int(x), 0x130, 0xf, 0xf, false));
}

__device__ __forceinline__ void sincos4(float4 th, float sn[4], float cs[4]) {
    __sincosf(th.x, &sn[0], &cs[0]);
    __sincosf(th.y, &sn[1], &cs[1]);
    __sincosf(th.z, &sn[2], &cs[2]);
    __sincosf(th.w, &sn[3], &cs[3]);
}

// ---------- kernel 1: per-stage collapsed coefficients ----------
__global__ __launch_bounds__(64)
void coef_kernel(const float* __restrict__ thetas,  // [130,256]
                 float* __restrict__ coefs)         // ws: 128*3*64 float4
{
    const int s0   = blockIdx.x;    // 0..127 -> theta row s0+1
    const int lane = threadIdx.x;   // 0..63

    const float U  = 0.98f * 0.505f;                  // AT^2
    const float W  = 0.98f * 0.495f;                  // AR^2
    const float Gc = 0.98f * sqrtf(0.505f * 0.495f);  // AT*AR

    float4 th = *(const float4*)(thetas + (s0 + 1) * 256 + 4 * lane);
    float s[4], c[4];
    sincos4(th, s, c);

    float4 A, B, C;
    A.x = U * c[0] - W * c[1];   A.y = U * s[0] - W * s[1];   // E0
    A.z = U * c[1] - W * c[0];   A.w = U * s[1] - W * s[0];   // F0
    B.x = -Gc * (s[0] + s[1]);   B.y = Gc * (c[0] + c[1]);    // G0
    B.z = -Gc * (s[2] + s[3]);   B.w = Gc * (c[2] + c[3]);    // G1
    C.x = U * c[2] - W * c[3];   C.y = U * s[2] - W * s[3];   // E1
    C.z = U * c[3] - W * c[2];   C.w = U * s[3] - W * s[2];   // F1

    float4* cp = (float4*)coefs;
    cp[(s0 * 3 + 0) * 64 + lane] = A;
    cp[(s0 * 3 + 1) * 64 + lane] = B;
    cp[(s0 * 3 + 2) * 64 + lane] = C;
}

// ---------- kernel 2: mesh state chain ----------
__global__ __launch_bounds__(64, 1)
void neuropuls_mesh_kernel(const float* __restrict__ thetas,  // [130,256]
                           const float* __restrict__ coefs,   // ws (from k1)
                           float* __restrict__ out)           // re[65536] || im[65536]
{
    constexpr int N = 256;
    // 16 chunks x 8 stages; per chunk 8*3*64 float4 = 24 KB; double-buffered.
    __shared__ float4 cbuf[2][1536];

    const int lane = threadIdx.x;   // 0..63
    const int col  = blockIdx.x;    // 0..255

    const float BT = sqrtf(0.98f * 0.01f);   // CR a*sqrt(CT)
    const float BR = sqrtf(0.98f * 0.99f);   // CR thru amplitude

    float vr[4] = {0.f, 0.f, 0.f, 0.f};
    float vi[4] = {0.f, 0.f, 0.f, 0.f};

    // arch0 = diag(exp(i*theta[0]))
    {
        const float th0 = thetas[col];
        float s0, c0;
        __sincosf(th0, &s0, &c0);
        const int r0 = col - 4 * lane;
        if (0 <= r0 && r0 < 4) { vr[r0] = c0; vi[r0] = s0; }
    }

    auto mstep = [&](const float4 A, const float4 B, const float4 C) {
        {   // pair 0: E=A.xy F=A.zw G=B.xy
            const float xr = vr[0], xi = vi[0], yr = vr[1], yi = vi[1];
            vr[0] = A.x * xr - A.y * xi + B.x * yr - B.y * yi;
            vi[0] = A.x * xi + A.y * xr + B.x * yi + B.y * yr;
            vr[1] = B.x * xr - B.y * xi + A.z * yr - A.w * yi;
            vi[1] = B.x * xi + B.y * xr + A.z * yi + A.w * yr;
        }
        {   // pair 1: E=C.xy F=C.zw G=B.zw
            const float xr = vr[2], xi = vi[2], yr = vr[3], yi = vi[3];
            vr[2] = C.x * xr - C.y * xi + B.z * yr - B.w * yi;
            vi[2] = C.x * xi + C.y * xr + B.z * yi + B.w * yr;
            vr[3] = B.z * xr - B.w * xi + C.z * yr - C.w * yi;
            vi[3] = B.z * xi + B.w * xr + C.z * yi + C.w * yr;
        }
    };

    auto crossing = [&]() {
        float pv3r = dpp_up1(vr[3]);
        float pv3i = dpp_up1(vi[3]);
        float nv0r = dpp_dn1(vr[0]);
        float nv0i = dpp_dn1(vi[0]);
        {   // internal odd pair (4t+1, 4t+2)
            float xr = vr[1], xi = vi[1], yr = vr[2], yi = vi[2];
            vr[1] = BT * xr - BR * yi;  vi[1] = BT * xi + BR * yr;
            vr[2] = BT * yr - BR * xi;  vi[2] = BT * yi + BR * xr;
        }
        {   // pair (4t-1, 4t): lane 0 row 0 = thru
            float yr = vr[0], yi = vi[0];
            float nr = BT * yr - BR * pv3i;
            float ni = BT * yi + BR * pv3r;
            vr[0] = (lane == 0) ? BR * yr : nr;
            vi[0] = (lane == 0) ? BR * yi : ni;
        }
        {   // pair (4t+3, 4t+4): lane 63 row 255 = thru
            float xr = vr[3], xi = vi[3];
            float nr = BT * xr - BR * nv0i;
            float ni = BT * xi + BR * nv0r;
            vr[3] = (lane == 63) ? BR * xr : nr;
            vi[3] = (lane == 63) ? BR * xi : ni;
        }
    };

    // issue chunk c's 24 DMA segments (1 KB each) into cbuf[c&1]
    auto issue_chunk = [&](int c) {
        const float4* src = (const float4*)coefs + (c * 24) * 64 + lane;
        float4* dst = &cbuf[c & 1][0];
        #pragma unroll
        for (int j = 0; j < 24; ++j)
            __builtin_amdgcn_global_load_lds(
                (const __attribute__((address_space(1))) void*)(src + j * 64),
                (__attribute__((address_space(3))) void*)(dst + j * 64),
                16, 0, 0);
    };
    // read stage-k coefs of chunk-buffer cb
    auto rdc = [&](int cb, int k, float4& A, float4& B, float4& C) {
        const float4* p = &cbuf[cb][k * 192 + lane];
        A = p[0]; B = p[64]; C = p[128];
    };

    // ---- prologue: chunks 0,1 in flight; wait chunk 0 only ----
    issue_chunk(0);
    issue_chunk(1);
    asm volatile("s_waitcnt vmcnt(24)" ::: "memory");
    __builtin_amdgcn_sched_barrier(0);

    float4 cA, cB, cC;
    rdc(0, 0, cA, cB, cC);   // stage t=0 (s=1)

    // chunks 0..14: 8 stages each, all with crossing (t<=119 -> s<=120)
    for (int c = 0; c < 15; ++c) {
        const int cb = c & 1;
        #pragma unroll
        for (int k = 0; k < 8; ++k) {
            float4 nA, nB, nC;
            if (k < 7) rdc(cb, k + 1, nA, nB, nC);   // distance-1 prefetch
            mstep(cA, cB, cC);
            crossing();
            if (k < 7) { cA = nA; cB = nB; cC = nC; }
        }
        // ---- chunk boundary ----
        asm volatile("s_waitcnt lgkmcnt(0)" ::: "memory");  // cbuf[cb] reads done
        if (c < 14) {
            issue_chunk(c + 2);                              // overwrite cbuf[cb]
            asm volatile("s_waitcnt vmcnt(24)" ::: "memory"); // chunk c+1 landed
        } else {
            asm volatile("s_waitcnt vmcnt(0)" ::: "memory");  // last chunk landed
        }
        __builtin_amdgcn_sched_barrier(0);
        rdc((c + 1) & 1, 0, cA, cB, cC);   // stage 0 of next chunk
    }

    // chunk 15: stages t=120..127 (s=121..128); s=128 has no crossing
    {
        #pragma unroll
        for (int k = 0; k < 7; ++k) {
            float4 nA, nB, nC;
            rdc(1, k + 1, nA, nB, nC);
            mstep(cA, cB, cC);
            crossing();                    // s=121..127
            cA = nA; cB = nB; cC = nC;
        }
        mstep(cA, cB, cC);                 // s=128: mstep only
    }

    // final phase layer theta[129] (global, one-time)
    {
        float4 thF = *(const float4*)(thetas + 129 * N + 4 * lane);
        float sn[4], cs[4];
        sincos4(thF, sn, cs);
        #pragma unroll
        for (int j = 0; j < 4; ++j) {
            float r = vr[j], i = vi[j];
            vr[j] = cs[j] * r - sn[j] * i;
            vi[j] = cs[j] * i + sn[j] * r;
        }
    }

    // store PLANAR: real block then imag block, row-major [row][col]
    #pragma unroll
    for (int j = 0; j < 4; ++j) {
        const int idx = (4 * lane + j) * N + col;
        out[idx]         = vr[j];
        out[N * N + idx] = vi[j];
    }
}

extern "C" void kernel_launch(void* const* d_in, const int* in_sizes, int n_in,
                              void* d_out, int out_size, void* d_ws, size_t ws_size,
                              hipStream_t stream)
{
    const float* thetas = (const float*)d_in[0];   // [130,256] fp32
    float* out   = (float*)d_out;                  // planar: re[65536] || im[65536]
    float* coefs = (float*)d_ws;                   // 128*3*64 float4 = 384 KB
    (void)in_sizes; (void)n_in; (void)out_size; (void)ws_size;

    coef_kernel<<<dim3(128), dim3(64), 0, stream>>>(thetas, coefs);
    neuropuls_mesh_kernel<<<dim3(256), dim3(64), 0, stream>>>(thetas, coefs, out);
}

// Round 9
// 74.137 us; speedup vs baseline: 1.2220x; 1.0476x over previous
//
#include <hip/hip_runtime.h>

// NEUROPULS unitary mesh, N=256 — R12: R11 + distance-2 coef register
// pipeline + edge-constant crossing.
// R11 post-mortem: VALUBusy is clock-independent; R6's 12.2% with ~280
// issue-cy/stage implies effective clock ~1.7 GHz (DPM never ramps for
// these 40 us dispatches) and R11's implied duty is ~25% — ~350 cy/stage
// stall remains. Only remaining in-loop latency: 3 ds_read_b128/stage at
// distance-1 (scheduler may sink to use -> ~130 cy exposed each stage).
// Fix: 3-slot register pipeline, iteration k issues reads for stage k+2
// (~2 stages of slack). Chunk boundary moves to k=5: lgkm drain, issue
// chunk c+2, vmcnt(24) ==> chunk c+1 landed before k=6 reads it (same
// invariants R11 passed with). Crossing thru-path via per-lane constants
// (lane0/63: BT<-BR, BR<-0) removes 4 cndmask; DPP edge junk is *0.
// Coef layout (float4): [(stage*3+g)*64+lane], g in {A,B,C}:
//   A=(Er0,Ei0,Fr0,Fi0) B=(Gr0,Gi0,Gr1,Gi1) C=(Er1,Ei1,Fr1,Fi1)
//   E=U*p0-W*p1, F=U*p1-W*p0, G=i*g*(p0+p1); U=AT^2, W=AR^2, g=AT*AR
// (verified algebra, R8/R11 passed).

__device__ __forceinline__ float dpp_up1(float x) {   // wave_shr:1, n <- n-1
    return __int_as_float(__builtin_amdgcn_update_dpp(
        __float_as_int(x), __float_as_int(x), 0x138, 0xf, 0xf, false));
}
__device__ __forceinline__ float dpp_dn1(float x) {   // wave_shl:1, n <- n+1
    return __int_as_float(__builtin_amdgcn_update_dpp(
        __float_as_int(x), __float_as_int(x), 0x130, 0xf, 0xf, false));
}

__device__ __forceinline__ void sincos4(float4 th, float sn[4], float cs[4]) {
    __sincosf(th.x, &sn[0], &cs[0]);
    __sincosf(th.y, &sn[1], &cs[1]);
    __sincosf(th.z, &sn[2], &cs[2]);
    __sincosf(th.w, &sn[3], &cs[3]);
}

// ---------- kernel 1: per-stage collapsed coefficients (unchanged) ----------
__global__ __launch_bounds__(64)
void coef_kernel(const float* __restrict__ thetas,  // [130,256]
                 float* __restrict__ coefs)         // ws: 128*3*64 float4
{
    const int s0   = blockIdx.x;    // 0..127 -> theta row s0+1
    const int lane = threadIdx.x;   // 0..63

    const float U  = 0.98f * 0.505f;                  // AT^2
    const float W  = 0.98f * 0.495f;                  // AR^2
    const float Gc = 0.98f * sqrtf(0.505f * 0.495f);  // AT*AR

    float4 th = *(const float4*)(thetas + (s0 + 1) * 256 + 4 * lane);
    float s[4], c[4];
    sincos4(th, s, c);

    float4 A, B, C;
    A.x = U * c[0] - W * c[1];   A.y = U * s[0] - W * s[1];   // E0
    A.z = U * c[1] - W * c[0];   A.w = U * s[1] - W * s[0];   // F0
    B.x = -Gc * (s[0] + s[1]);   B.y = Gc * (c[0] + c[1]);    // G0
    B.z = -Gc * (s[2] + s[3]);   B.w = Gc * (c[2] + c[3]);    // G1
    C.x = U * c[2] - W * c[3];   C.y = U * s[2] - W * s[3];   // E1
    C.z = U * c[3] - W * c[2];   C.w = U * s[3] - W * s[2];   // F1

    float4* cp = (float4*)coefs;
    cp[(s0 * 3 + 0) * 64 + lane] = A;
    cp[(s0 * 3 + 1) * 64 + lane] = B;
    cp[(s0 * 3 + 2) * 64 + lane] = C;
}

// ---------- kernel 2: mesh state chain ----------
__global__ __launch_bounds__(64, 1)
void neuropuls_mesh_kernel(const float* __restrict__ thetas,  // [130,256]
                           const float* __restrict__ coefs,   // ws (from k1)
                           float* __restrict__ out)           // re[65536] || im[65536]
{
    constexpr int N = 256;
    // 16 chunks x 8 stages; per chunk 8*3*64 float4 = 24 KB; double-buffered.
    __shared__ float4 cbuf[2][1536];

    const int lane = threadIdx.x;   // 0..63
    const int col  = blockIdx.x;    // 0..255

    const float BT = sqrtf(0.98f * 0.01f);   // CR a*sqrt(CT)
    const float BR = sqrtf(0.98f * 0.99f);   // CR thru amplitude
    // per-lane edge constants: lane0 row0 / lane63 row255 are thru paths
    const float eT0 = (lane == 0)  ? BR : BT, eR0 = (lane == 0)  ? 0.f : BR;
    const float eT3 = (lane == 63) ? BR : BT, eR3 = (lane == 63) ? 0.f : BR;

    float vr[4] = {0.f, 0.f, 0.f, 0.f};
    float vi[4] = {0.f, 0.f, 0.f, 0.f};

    // arch0 = diag(exp(i*theta[0]))
    {
        const float th0 = thetas[col];
        float s0, c0;
        __sincosf(th0, &s0, &c0);
        const int r0 = col - 4 * lane;
        if (0 <= r0 && r0 < 4) { vr[r0] = c0; vi[r0] = s0; }
    }

    // ---- register pipeline: slot0 = stage being computed, slot1 = +1,
    //      slot2 = +2 (ds_reads land here) ----
    float4 A0, B0, C0, A1, B1, C1, A2, B2, C2;

    auto rd2 = [&](int buf, int k) {        // read stage-k coefs of buffer
        const float4* p = &cbuf[buf][k * 192 + lane];
        A2 = p[0]; B2 = p[64]; C2 = p[128];
    };

    auto mstep = [&]() {
        {   // pair 1 first (ages vr[3] before the crossing DPP reads it)
            const float xr = vr[2], xi = vi[2], yr = vr[3], yi = vi[3];
            vr[2] = C0.x * xr - C0.y * xi + B0.z * yr - B0.w * yi;
            vi[2] = C0.x * xi + C0.y * xr + B0.z * yi + B0.w * yr;
            vr[3] = B0.z * xr - B0.w * xi + C0.z * yr - C0.w * yi;
            vi[3] = B0.z * xi + B0.w * xr + C0.z * yi + C0.w * yr;
        }
        {   // pair 0
            const float xr = vr[0], xi = vi[0], yr = vr[1], yi = vi[1];
            vr[0] = A0.x * xr - A0.y * xi + B0.x * yr - B0.y * yi;
            vi[0] = A0.x * xi + A0.y * xr + B0.x * yi + B0.y * yr;
            vr[1] = B0.x * xr - B0.y * xi + A0.z * yr - A0.w * yi;
            vi[1] = B0.x * xi + B0.y * xr + A0.z * yi + A0.w * yr;
        }
    };

    auto crossing = [&]() {
        const float pv3r = dpp_up1(vr[3]);
        const float pv3i = dpp_up1(vi[3]);
        const float nv0r = dpp_dn1(vr[0]);
        const float nv0i = dpp_dn1(vi[0]);
        {   // internal odd pair (4t+1, 4t+2) — no DPP inputs
            const float xr = vr[1], xi = vi[1], yr = vr[2], yi = vi[2];
            vr[1] = BT * xr - BR * yi;  vi[1] = BT * xi + BR * yr;
            vr[2] = BT * yr - BR * xi;  vi[2] = BT * yi + BR * xr;
        }
        // edge pairs via per-lane constants (thru lanes multiply DPP junk by 0)
        vr[0] = eT0 * vr[0] - eR0 * pv3i;  vi[0] = eT0 * vi[0] + eR0 * pv3r;
        vr[3] = eT3 * vr[3] - eR3 * nv0i;  vi[3] = eT3 * vi[3] + eR3 * nv0r;
    };

    auto rotate = [&]() {
        A0 = A1; B0 = B1; C0 = C1;
        A1 = A2; B1 = B2; C1 = C2;
    };

    // issue chunk c's 24 DMA segments (1 KB each) into cbuf[c&1]
    auto issue_chunk = [&](int c) {
        const float4* src = (const float4*)coefs + (c * 24) * 64 + lane;
        float4* dst = &cbuf[c & 1][0];
        #pragma unroll
        for (int j = 0; j < 24; ++j)
            __builtin_amdgcn_global_load_lds(
                (const __attribute__((address_space(1))) void*)(src + j * 64),
                (__attribute__((address_space(3))) void*)(dst + j * 64),
                16, 0, 0);
    };

    // ---- prologue: chunks 0,1 in flight; chunk 0 landed after vmcnt(24) ----
    issue_chunk(0);
    issue_chunk(1);
    asm volatile("s_waitcnt vmcnt(24)" ::: "memory");
    __builtin_amdgcn_sched_barrier(0);
    {   // slot0 = stage 0, slot1 = stage 1
        const float4* p = &cbuf[0][lane];
        A0 = p[0]; B0 = p[64]; C0 = p[128];
        p = &cbuf[0][192 + lane];
        A1 = p[0]; B1 = p[64]; C1 = p[128];
    }

    // chunks 0..14: 8 stages each, all with crossing (t=0..119 -> s=1..120)
    for (int c = 0; c < 15; ++c) {
        const int cb = c & 1;
        #pragma unroll
        for (int k = 0; k < 5; ++k) {       // k=0..4: read k+2, compute k
            rd2(cb, k + 2);
            mstep(); crossing(); rotate();
        }
        // k=5: read (cb,7); drain reads of cbuf[cb]; refill it with c+2;
        //      vmcnt(24) ==> chunk c+1 fully landed before k=6 reads it
        rd2(cb, 7);
        asm volatile("s_waitcnt lgkmcnt(0)" ::: "memory");
        __builtin_amdgcn_sched_barrier(0);
        if (c <= 13) {
            issue_chunk(c + 2);
            asm volatile("s_waitcnt vmcnt(24)" ::: "memory");
        } else {
            asm volatile("s_waitcnt vmcnt(0)" ::: "memory");   // chunk 15 landed
        }
        __builtin_amdgcn_sched_barrier(0);
        mstep(); crossing(); rotate();
        rd2(cb ^ 1, 0);                      // k=6: first stage of chunk c+1
        mstep(); crossing(); rotate();
        rd2(cb ^ 1, 1);                      // k=7
        mstep(); crossing(); rotate();
    }

    // chunk 15 (buffer 1): stages t=120..127 (s=121..128)
    #pragma unroll
    for (int k = 0; k < 6; ++k) {            // t=120..125 (s=121..126)
        rd2(1, k + 2);
        mstep(); crossing(); rotate();
    }
    mstep(); crossing(); rotate();           // t=126 (s=127, last crossing)
    mstep();                                 // t=127 (s=128, mstep only)

    // final phase layer theta[129] (global, one-time)
    {
        float4 thF = *(const float4*)(thetas + 129 * N + 4 * lane);
        float sn[4], cs[4];
        sincos4(thF, sn, cs);
        #pragma unroll
        for (int j = 0; j < 4; ++j) {
            float r = vr[j], i = vi[j];
            vr[j] = cs[j] * r - sn[j] * i;
            vi[j] = cs[j] * i + sn[j] * r;
        }
    }

    // store PLANAR: real block then imag block, row-major [row][col]
    #pragma unroll
    for (int j = 0; j < 4; ++j) {
        const int idx = (4 * lane + j) * N + col;
        out[idx]         = vr[j];
        out[N * N + idx] = vi[j];
    }
}

extern "C" void kernel_launch(void* const* d_in, const int* in_sizes, int n_in,
                              void* d_out, int out_size, void* d_ws, size_t ws_size,
                              hipStream_t stream)
{
    const float* thetas = (const float*)d_in[0];   // [130,256] fp32
    float* out   = (float*)d_out;                  // planar: re[65536] || im[65536]
    float* coefs = (float*)d_ws;                   // 128*3*64 float4 = 384 KB
    (void)in_sizes; (void)n_in; (void)out_size; (void)ws_size;

    coef_kernel<<<dim3(128), dim3(64), 0, stream>>>(thetas, coefs);
    neuropuls_mesh_kernel<<<dim3(256), dim3(64), 0, stream>>>(thetas, coefs, out);
}